// Round 13
// baseline (410.669 us; speedup 1.0000x reference)
//
#include <hip/hip_runtime.h>
#include <hip/hip_cooperative_groups.h>

#define NN 65536
#define NE 1048576
#define INDIM 512
#define HID 128
#define NSB 256   // binning blocks (4096 edges each)

typedef __attribute__((ext_vector_type(8))) short bf16x8;
typedef __attribute__((ext_vector_type(16))) float f32x16;

// ---------------- W prep helper: f32 [K][128] -> MFMA-fragment-packed split-bf16 ----------------
__device__ __forceinline__ void prep_one(const float* __restrict__ W, unsigned short* __restrict__ P,
                                         int t) {
    int l = t & 63;
    int h = (t >> 6) & 1;
    int n = (t >> 7) & 3;
    int k0 = t >> 9;
    int colg = n * 32 + (l & 31);
    int kbase = k0 * 16 + (l >> 5) * 8;
    bf16x8 v;
#pragma unroll
    for (int j = 0; j < 8; j++) {
        float f = W[(size_t)(kbase + j) * 128 + colg];
        unsigned b = __float_as_uint(f);
        if (h == 0) {
            v[j] = (short)(b >> 16);
        } else {
            float lf = f - __uint_as_float(b & 0xFFFF0000u);
            v[j] = (short)(__float_as_uint(lf) >> 16);
        }
    }
    *(bf16x8*)(P + (size_t)t * 8) = v;
}

// ---------------- fused CSR build + weight prep (cooperative, grid 256 x 256) ----------------
__global__ __launch_bounds__(256, 1) void k_csr(
        const int* __restrict__ src, const int* __restrict__ dst, const float* __restrict__ ew,
        const float* __restrict__ W1, const float* __restrict__ W2,
        int* __restrict__ ghist, int* __restrict__ bsum1,
        unsigned* __restrict__ e1sd, float* __restrict__ e1ew,
        uint2* __restrict__ edata, int* __restrict__ row_beg, int* __restrict__ row_end,
        float* __restrict__ dinv, unsigned short* __restrict__ bp1, unsigned short* __restrict__ bp2) {
    cooperative_groups::grid_group grid = cooperative_groups::this_grid();
    __shared__ int si0[256];
    __shared__ int si1[256];
    __shared__ int si2[256];
    __shared__ float sf0[256];
    const int b = blockIdx.x, t = threadIdx.x;
    const int base = b * 4096;

    // Phase H: per-block LDS histogram over lo8(dst)
    si0[t] = 0;
    __syncthreads();
    for (int r = 0; r < 16; r++) atomicAdd(&si0[dst[base + r * 256 + t] & 255], 1);
    __syncthreads();
    ghist[t * NSB + b] = si0[t];  // bin-major [bin][block]
    __threadfence();
    grid.sync();

    // Phase S1: block b scans bin-row b (exclusive within bin); bsum1[b] = bin total
    {
        int i = b * 256 + t;
        int v = ghist[i];
        si0[t] = v;
        __syncthreads();
        for (int off = 1; off < 256; off <<= 1) {
            int u = (t >= off) ? si0[t - off] : 0;
            __syncthreads();
            si0[t] += u;
            __syncthreads();
        }
        ghist[i] = si0[t] - v;
        if (t == 255) bsum1[b] = si0[255];
    }
    __threadfence();
    grid.sync();

    // Phase S2: block 0 scans bin totals -> bin bases; blocks 1..80 pack W1/W2 (independent)
    if (b == 0) {
        int v = bsum1[t];
        si0[t] = v;
        __syncthreads();
        for (int off = 1; off < 256; off <<= 1) {
            int u = (t >= off) ? si0[t - off] : 0;
            __syncthreads();
            si0[t] += u;
            __syncthreads();
        }
        bsum1[t] = si0[t] - v;
    } else if (b <= 80) {
        int idx = (b - 1) * 256 + t;
        if (idx < 16384) prep_one(W1, bp1, idx);
        else prep_one(W2, bp2, idx - 16384);
    }
    __threadfence();
    grid.sync();

    // Phase SC1: scatter into lo8-bin segments (cursor = bin base + within-bin prefix)
    si0[t] = bsum1[t] + ghist[t * NSB + b];
    __syncthreads();
    for (int r = 0; r < 16; r++) {
        int e = base + r * 256 + t;
        int d = dst[e];
        int p = atomicAdd(&si0[d & 255], 1);  // LDS; (bin,block) region private
        e1sd[p] = (unsigned)src[e] | ((unsigned)(d >> 8) << 16);
        e1ew[p] = ew[e];
    }
    __threadfence();
    grid.sync();

    // Phase SC2: block b = bin b -> final dst-grouped edata + rows + dinv
    {
        si0[t] = 0;   // cnt
        sf0[t] = 0.f; // deg sum
        __syncthreads();
        const int binstart = bsum1[b];
        const int binend = (b == 255) ? NE : bsum1[b + 1];
        for (int i = binstart + t; i < binend; i += 256) {
            unsigned u = e1sd[i];
            atomicAdd(&si0[u >> 16], 1);
            atomicAdd(&sf0[u >> 16], e1ew[i]);
        }
        __syncthreads();
        int v = si0[t];
        si1[t] = v;
        __syncthreads();
        for (int off = 1; off < 256; off <<= 1) {
            int u = (t >= off) ? si1[t - off] : 0;
            __syncthreads();
            si1[t] += u;
            __syncthreads();
        }
        int d = (t << 8) | b;
        int beg = binstart + si1[t] - v;
        row_beg[d] = beg;
        row_end[d] = beg + v;
        dinv[d] = rsqrtf(1.0f + sf0[t]);  // deg >= 1 (self-loop), ew >= 0
        si2[t] = beg;
        __syncthreads();
        for (int i = binstart + t; i < binend; i += 256) {
            unsigned u = e1sd[i];
            int p = atomicAdd(&si2[u >> 16], 1);  // LDS; same-dst edges stay contiguous
            edata[p] = make_uint2(u & 0xFFFFu, __float_as_uint(e1ew[i]));
        }
    }
}

// ---------------- split-bf16 MFMA GEMM: C[M,128] = A[M,K] @ W[K,128], C in bf16 ----------------
__device__ __forceinline__ void split8(const float4& a0, const float4& a1,
                                       bf16x8& hi, bf16x8& lo) {
    float f[8] = {a0.x, a0.y, a0.z, a0.w, a1.x, a1.y, a1.z, a1.w};
#pragma unroll
    for (int i = 0; i < 8; i++) {
        unsigned b = __float_as_uint(f[i]);
        unsigned hb = b & 0xFFFF0000u;
        float lf = f[i] - __uint_as_float(hb);
        hi[i] = (short)(hb >> 16);
        lo[i] = (short)(__float_as_uint(lf) >> 16);
    }
}

__device__ __forceinline__ unsigned short f2bf_rne(float v) {
    unsigned u = __float_as_uint(v);
    unsigned r = (u + 0x7FFFu + ((u >> 16) & 1u)) >> 16;
    return (unsigned short)r;
}

// Stage one BK=32 chunk (64 rows). f32 path: 2 A + 4 B loads/thread (L=6).
// BF16A path: 1 A + 4 B loads/thread (L=5).
template <int K, bool BF16A>
__device__ __forceinline__ void stage_chunk(const float* __restrict__ A,
                                            const unsigned short* __restrict__ Ab,
                                            int rowbase,
                                            const unsigned short* __restrict__ Bp,
                                            int c, int tid, char* As, unsigned short* Bs) {
    const int w = tid >> 6;
    if (BF16A) {
        int row = tid & 63;
        int kk2lh = tid >> 6;
        const char* srcp = (const char*)Ab + ((size_t)(rowbase + row) * 128 + c * 32 + kk2lh * 8) * 2;
        char* dst = As + (size_t)(w * 64) * 16;
        __builtin_amdgcn_global_load_lds((const __attribute__((address_space(1))) void*)srcp,
                                         (__attribute__((address_space(3))) void*)dst, 16, 0, 0);
    } else {
#pragma unroll
        for (int q = 0; q < 2; ++q) {
            int lh = (tid >> 7) & 1;
            int row = (tid >> 1) & 63;
            int g = (tid & 1) ^ ((row >> 2) & 1);
            const float* srcp = A + (size_t)(rowbase + row) * K + c * 32 + q * 16 + lh * 8 + g * 4;
            char* dst = As + (size_t)(q * 256 + w * 64) * 16;
            __builtin_amdgcn_global_load_lds((const __attribute__((address_space(1))) void*)srcp,
                                             (__attribute__((address_space(3))) void*)dst, 16, 0, 0);
        }
    }
    const char* bsrc0 = (const char*)Bp + (size_t)c * 16384;
#pragma unroll
    for (int q = 0; q < 4; ++q) {
        const char* srcp = bsrc0 + (size_t)(q * 256 + tid) * 16;
        char* dst = (char*)Bs + (size_t)(q * 256 + w * 64) * 16;
        __builtin_amdgcn_global_load_lds((const __attribute__((address_space(1))) void*)srcp,
                                         (__attribute__((address_space(3))) void*)dst, 16, 0, 0);
    }
}

// Block: 64 rows x 128 cols, 4 waves, wave tile 32x64.
// 3-buffer LDS pipeline, counted vmcnt (never 0 in steady state), raw s_barrier.
template <int K, bool BF16A>
__global__ __launch_bounds__(256, 2) void k_gemm_mfma(const float* __restrict__ A,
                                                      const unsigned short* __restrict__ Ab,
                                                      const unsigned short* __restrict__ Bp,
                                                      unsigned short* __restrict__ Cb) {
    constexpr int NC = K / 32;
    __shared__ __align__(16) char As[3][8192];             // f32: 8KB; bf16A: first 4KB used
    __shared__ __align__(16) unsigned short Bs[3][8192];   // 3 x 16KB
    const int tid = threadIdx.x;
    const int w = tid >> 6;
    const int lane = tid & 63;
    const int l31 = lane & 31;
    const int lhalf = lane >> 5;
    const int rowbase = blockIdx.x * 64;
    const int ncol = (w & 1) * 2;
    const int r = (w >> 1) * 32 + l31;
    const int xr = (l31 >> 2) & 1;

    f32x16 acc[2] = {};

    stage_chunk<K, BF16A>(A, Ab, rowbase, Bp, 0, tid, As[0], Bs[0]);
    stage_chunk<K, BF16A>(A, Ab, rowbase, Bp, 1, tid, As[1], Bs[1]);

    for (int c = 0; c < NC; ++c) {
        if (c > 0) {
            __builtin_amdgcn_s_barrier();   // buf (c-1)%3 free
            asm volatile("" ::: "memory");
            __builtin_amdgcn_sched_barrier(0);
        }
        if (c + 2 < NC) {
            int b = (c + 2) % 3;
            stage_chunk<K, BF16A>(A, Ab, rowbase, Bp, c + 2, tid, As[b], Bs[b]);
        }
        int rem = NC - 1 - c;
        if (BF16A) {
            if (rem >= 2)      asm volatile("s_waitcnt vmcnt(10)" ::: "memory");
            else if (rem == 1) asm volatile("s_waitcnt vmcnt(5)" ::: "memory");
            else               asm volatile("s_waitcnt vmcnt(0)" ::: "memory");
        } else {
            if (rem >= 2)      asm volatile("s_waitcnt vmcnt(12)" ::: "memory");
            else if (rem == 1) asm volatile("s_waitcnt vmcnt(6)" ::: "memory");
            else               asm volatile("s_waitcnt vmcnt(0)" ::: "memory");
        }
        __builtin_amdgcn_s_barrier();       // chunk c visible
        const int cur = c % 3;
#pragma unroll
        for (int kk = 0; kk < 2; ++kk) {
            bf16x8 ahi, alo;
            if (BF16A) {
                int gidx = ((kk * 2 + lhalf) * 64 + r) * 16;
                ahi = *(const bf16x8*)&As[cur][gidx];
            } else {
                const float* Af = (const float*)As[cur];
                int bg = ((kk * 2 + lhalf) * 64 + r) * 2;
                float4 aa = *(const float4*)&Af[(size_t)(bg + xr) * 4];        // k+0..3
                float4 ab = *(const float4*)&Af[(size_t)(bg + (1 ^ xr)) * 4];  // k+4..7
                split8(aa, ab, ahi, alo);
            }
#pragma unroll
            for (int n = 0; n < 2; ++n) {
                int f = (ncol + n) * 2;
                bf16x8 bhi = *(const bf16x8*)&Bs[cur][(size_t)((kk * 8 + f) * 64 + lane) * 8];
                bf16x8 blo = *(const bf16x8*)&Bs[cur][(size_t)((kk * 8 + f + 1) * 64 + lane) * 8];
                acc[n] = __builtin_amdgcn_mfma_f32_32x32x16_bf16(ahi, bhi, acc[n], 0, 0, 0);
                acc[n] = __builtin_amdgcn_mfma_f32_32x32x16_bf16(ahi, blo, acc[n], 0, 0, 0);
                if (!BF16A)
                    acc[n] = __builtin_amdgcn_mfma_f32_32x32x16_bf16(alo, bhi, acc[n], 0, 0, 0);
            }
        }
    }

    const int rbase = rowbase + (w >> 1) * 32 + 4 * lhalf;
#pragma unroll
    for (int n = 0; n < 2; ++n) {
        const int col = (ncol + n) * 32 + l31;
#pragma unroll
        for (int rr = 0; rr < 16; ++rr) {
            int rout = rbase + (rr & 3) + 8 * (rr >> 2);
            Cb[(size_t)rout * HID + col] = f2bf_rne(acc[n][rr]);
        }
    }
}

// ---------------- aggregation: out[d] = di*(sum dinv[s]*ew*h[s]) + di^2*h[d] + b ----------------
// RELU=true: emit bf16 a1 (abuf). RELU=false: emit f32 to out.
__device__ __forceinline__ float2 up2(unsigned u) {
    float2 r;
    r.x = __uint_as_float(u << 16);
    r.y = __uint_as_float(u & 0xFFFF0000u);
    return r;
}

template <bool RELU>
__global__ __launch_bounds__(256) void k_agg(const unsigned short* __restrict__ hb,
                                             const float* __restrict__ dinv,
                                             const int* __restrict__ row_beg,
                                             const int* __restrict__ row_end,
                                             const uint2* __restrict__ edata,
                                             const float* __restrict__ bias,
                                             float* __restrict__ out,
                                             unsigned* __restrict__ abuf) {
    int d = (blockIdx.x * blockDim.x + threadIdx.x) >> 6;  // one wave per node
    int lane = threadIdx.x & 63;
    float di = dinv[d];
    float2 hv = up2(((const unsigned*)(hb + (size_t)d * HID))[lane]);
    int beg = row_beg[d], end = row_end[d];
    float ex = 0.f, ey = 0.f;
    int e = beg;
    for (; e + 15 < end; e += 16) {
        uint2 u[16];
        unsigned g[16];
        float dv[16];
#pragma unroll
        for (int q = 0; q < 16; q++) u[q] = edata[e + q];
#pragma unroll
        for (int q = 0; q < 16; q++) {
            g[q] = ((const unsigned*)(hb + (size_t)u[q].x * HID))[lane];
            dv[q] = dinv[u[q].x];
        }
#pragma unroll
        for (int q = 0; q < 16; q++) {
            float2 vv = up2(g[q]);
            float c = dv[q] * __uint_as_float(u[q].y);
            ex += c * vv.x;
            ey += c * vv.y;
        }
    }
    for (; e + 3 < end; e += 4) {
        uint2 u[4];
        unsigned g[4];
        float dv[4];
#pragma unroll
        for (int q = 0; q < 4; q++) u[q] = edata[e + q];
#pragma unroll
        for (int q = 0; q < 4; q++) {
            g[q] = ((const unsigned*)(hb + (size_t)u[q].x * HID))[lane];
            dv[q] = dinv[u[q].x];
        }
#pragma unroll
        for (int q = 0; q < 4; q++) {
            float2 vv = up2(g[q]);
            float c = dv[q] * __uint_as_float(u[q].y);
            ex += c * vv.x;
            ey += c * vv.y;
        }
    }
    for (; e < end; ++e) {
        uint2 u = edata[e];
        float2 v = up2(((const unsigned*)(hb + (size_t)u.x * HID))[lane]);
        float c = dinv[u.x] * __uint_as_float(u.y);
        ex += c * v.x;
        ey += c * v.y;
    }
    float2 bv = ((const float2*)bias)[lane];
    float selfc = di * di;
    float ax = di * ex + selfc * hv.x + bv.x;
    float ay = di * ey + selfc * hv.y + bv.y;
    if (RELU) {
        ax = fmaxf(ax, 0.f);
        ay = fmaxf(ay, 0.f);
        unsigned pk = (unsigned)f2bf_rne(ax) | ((unsigned)f2bf_rne(ay) << 16);
        abuf[(size_t)d * 64 + lane] = pk;
    } else {
        float2 rr;
        rr.x = ax;
        rr.y = ay;
        ((float2*)(out + (size_t)d * HID))[lane] = rr;
    }
}

extern "C" void kernel_launch(void* const* d_in, const int* in_sizes, int n_in,
                              void* d_out, int out_size, void* d_ws, size_t ws_size,
                              hipStream_t stream) {
    const float* x = (const float*)d_in[0];
    const int* ei = (const int*)d_in[1];
    const float* ew = (const float*)d_in[2];
    const float* W1 = (const float*)d_in[3];
    const float* b1 = (const float*)d_in[4];
    const float* W2 = (const float*)d_in[5];
    const float* b2 = (const float*)d_in[6];
    float* out = (float*)d_out;

    // Workspace layout — fully disjoint:
    char* ws = (char*)d_ws;
    unsigned short* hb = (unsigned short*)(ws + 0);          // 16 MB bf16 h
    uint2* edata    = (uint2*)(ws + 16777216);               //  8 MB final grouped edges
    int*   ghist    = (int*)(ws + 25165824);                 // 256 KB [256 bins][256 blocks]
    int*   bsum1    = (int*)(ws + 25427968);                 //  1 KB
    unsigned* e1sd  = (unsigned*)(ws + 25428992);            //  4 MB pass-1 packed (dsthi|src)
    float* e1ew     = (float*)(ws + 29623296);               //  4 MB pass-1 ew
    int*   row_beg  = (int*)(ws + 33817600);                 // 256 KB
    int*   row_end  = (int*)(ws + 34079744);                 // 256 KB
    float* dinv     = (float*)(ws + 34341888);               // 256 KB
    unsigned short* bp1 = (unsigned short*)(ws + 34604032);  // 256 KB
    unsigned short* bp2 = (unsigned short*)(ws + 34866176);  //  64 KB
    unsigned* a1b   = (unsigned*)(ws + 35651584);            //  16 MB bf16 a1

    // CSR build + weight prep — ONE cooperative kernel (grid 256 = 1 block/CU)
    const int* srcp = ei;
    const int* dstp = ei + NE;
    const float* ewp = ew;
    const float* w1p = W1;
    const float* w2p = W2;
    void* kargs[] = {(void*)&srcp, (void*)&dstp, (void*)&ewp, (void*)&w1p, (void*)&w2p,
                     (void*)&ghist, (void*)&bsum1, (void*)&e1sd, (void*)&e1ew,
                     (void*)&edata, (void*)&row_beg, (void*)&row_end, (void*)&dinv,
                     (void*)&bp1, (void*)&bp2};
    hipLaunchCooperativeKernel((const void*)k_csr, dim3(NSB), dim3(256), kargs, 0, stream);

    // layer 1: hb = bf16(x @ W1) ; a1 = relu(agg(hb) + b1) -> bf16 a1b
    k_gemm_mfma<INDIM, false><<<NN / 64, 256, 0, stream>>>(x, nullptr, bp1, hb);
    k_agg<true><<<NN / 4, 256, 0, stream>>>(hb, dinv, row_beg, row_end, edata, b1, nullptr, a1b);

    // layer 2: hb = bf16(a1 @ W2) ; z = agg(hb) + b2 -> d_out (f32)
    k_gemm_mfma<HID, true><<<NN / 64, 256, 0, stream>>>(nullptr, (const unsigned short*)a1b, bp2, hb);
    k_agg<false><<<NN / 4, 256, 0, stream>>>(hb, dinv, row_beg, row_end, edata, b2, out, nullptr);
}

// Round 14
// 199.024 us; speedup vs baseline: 2.0634x; 2.0634x over previous
//
#include <hip/hip_runtime.h>

#define NN 65536
#define NE 1048576
#define INDIM 512
#define HID 128
#define NSB 256   // binning blocks (4096 edges each)

typedef __attribute__((ext_vector_type(8))) short bf16x8;
typedef __attribute__((ext_vector_type(16))) float f32x16;

// ---------------- pass 1: per-block LDS histogram over lo8(dst), 4096 edges/block ----------------
__global__ void k_h1(const int* __restrict__ dst, int* __restrict__ ghist) {
    __shared__ int hcnt[256];
    hcnt[threadIdx.x] = 0;
    __syncthreads();
    int base = blockIdx.x * 4096;
#pragma unroll
    for (int r = 0; r < 16; r++)
        atomicAdd(&hcnt[dst[base + r * 256 + threadIdx.x] & 255], 1);  // LDS atomic
    __syncthreads();
    ghist[threadIdx.x * NSB + blockIdx.x] = hcnt[threadIdx.x];  // bin-major [bin][block]
}

// ---------------- generic 256-wide in-place exclusive scan level ----------------
__global__ void k_scan_ex(int* data, int* bsum, int n) {
    __shared__ int tmp[256];
    int i = blockIdx.x * 256 + threadIdx.x;
    int v = (i < n) ? data[i] : 0;
    tmp[threadIdx.x] = v;
    __syncthreads();
    for (int off = 1; off < 256; off <<= 1) {
        int t = (threadIdx.x >= off) ? tmp[threadIdx.x - off] : 0;
        __syncthreads();
        tmp[threadIdx.x] += t;
        __syncthreads();
    }
    if (i < n) data[i] = tmp[threadIdx.x] - v;  // exclusive
    if (threadIdx.x == 255 && bsum) bsum[blockIdx.x] = tmp[255];
}

__global__ void k_addback(int* data, const int* __restrict__ bsum) {
    int i = blockIdx.x * 256 + threadIdx.x;
    data[i] += bsum[blockIdx.x];
}

// ---------------- pass 1 scatter: group edges by lo8(dst), LDS cursors, 4096 edges/block ----------------
// packed: e1sd = (dst_hi8 << 16) | src   (src < 2^16)
__global__ void k_s1(const int* __restrict__ src, const int* __restrict__ dst,
                     const float* __restrict__ ew, const int* __restrict__ ghist,
                     unsigned* __restrict__ e1sd, float* __restrict__ e1ew) {
    __shared__ int cur[256];
    cur[threadIdx.x] = ghist[threadIdx.x * NSB + blockIdx.x];  // scanned global base
    __syncthreads();
    int base = blockIdx.x * 4096;
#pragma unroll
    for (int r = 0; r < 16; r++) {
        int e = base + r * 256 + threadIdx.x;
        int d = dst[e];
        int p = atomicAdd(&cur[d & 255], 1);  // LDS atomic; (block,bin) region private
        e1sd[p] = (unsigned)src[e] | ((unsigned)(d >> 8) << 16);
        e1ew[p] = ew[e];
    }
}

// ---------------- pass 2: one block per bin -> final dst-grouped edata + rows + dinv ----------------
__global__ void k_s2(const int* __restrict__ ghist, const unsigned* __restrict__ e1sd,
                     const float* __restrict__ e1ew,
                     uint2* __restrict__ edata, int* __restrict__ row_beg,
                     int* __restrict__ row_end, float* __restrict__ dinv) {
    __shared__ int cnt[256];
    __shared__ float degs[256];
    __shared__ int tmp[256];
    __shared__ int curx[256];
    const int bin = blockIdx.x;
    const int t = threadIdx.x;
    cnt[t] = 0;
    degs[t] = 0.f;
    __syncthreads();
    const int binstart = ghist[bin * NSB];
    const int binend = (bin == 255) ? NE : ghist[(bin + 1) * NSB];
    for (int i = binstart + t; i < binend; i += 256) {
        unsigned u = e1sd[i];
        int j = u >> 16;
        atomicAdd(&cnt[j], 1);           // LDS
        atomicAdd(&degs[j], e1ew[i]);    // LDS float
    }
    __syncthreads();
    // exclusive scan of cnt
    int v = cnt[t];
    tmp[t] = v;
    __syncthreads();
    for (int off = 1; off < 256; off <<= 1) {
        int u = (t >= off) ? tmp[t - off] : 0;
        __syncthreads();
        tmp[t] += u;
        __syncthreads();
    }
    int offt = tmp[t] - v;
    int d = (t << 8) | bin;
    int beg = binstart + offt;
    row_beg[d] = beg;
    row_end[d] = beg + v;
    dinv[d] = rsqrtf(1.0f + degs[t]);  // deg >= 1 (self-loop), ew >= 0
    curx[t] = beg;
    __syncthreads();
    for (int i = binstart + t; i < binend; i += 256) {
        unsigned u = e1sd[i];
        int p = atomicAdd(&curx[u >> 16], 1);  // LDS; same-dst edges stay contiguous
        edata[p] = make_uint2(u & 0xFFFFu, __float_as_uint(e1ew[i]));  // raw ew; dinv folded in agg
    }
}

// ---------------- W prep (fused W1+W2): f32 [K][128] -> MFMA-fragment-packed split-bf16 ----------------
__device__ __forceinline__ void prep_one(const float* __restrict__ W, unsigned short* __restrict__ P,
                                         int t) {
    int l = t & 63;
    int h = (t >> 6) & 1;
    int n = (t >> 7) & 3;
    int k0 = t >> 9;
    int colg = n * 32 + (l & 31);
    int kbase = k0 * 16 + (l >> 5) * 8;
    bf16x8 v;
#pragma unroll
    for (int j = 0; j < 8; j++) {
        float f = W[(size_t)(kbase + j) * 128 + colg];
        unsigned b = __float_as_uint(f);
        if (h == 0) {
            v[j] = (short)(b >> 16);
        } else {
            float lf = f - __uint_as_float(b & 0xFFFF0000u);
            v[j] = (short)(__float_as_uint(lf) >> 16);
        }
    }
    *(bf16x8*)(P + (size_t)t * 8) = v;
}

__global__ void k_prep_pack2(const float* __restrict__ W1, unsigned short* __restrict__ P1,
                             const float* __restrict__ W2, unsigned short* __restrict__ P2) {
    int t = blockIdx.x * 256 + threadIdx.x;
    if (t < 16384) prep_one(W1, P1, t);                      // K=512
    else if (t < 16384 + 4096) prep_one(W2, P2, t - 16384);  // K=128
}

// ---------------- split-bf16 MFMA GEMM: C[M,128] = A[M,K] @ W[K,128], C in bf16 ----------------
__device__ __forceinline__ void split8(const float4& a0, const float4& a1,
                                       bf16x8& hi, bf16x8& lo) {
    float f[8] = {a0.x, a0.y, a0.z, a0.w, a1.x, a1.y, a1.z, a1.w};
#pragma unroll
    for (int i = 0; i < 8; i++) {
        unsigned b = __float_as_uint(f[i]);
        unsigned hb = b & 0xFFFF0000u;
        float lf = f[i] - __uint_as_float(hb);
        hi[i] = (short)(hb >> 16);
        lo[i] = (short)(__float_as_uint(lf) >> 16);
    }
}

__device__ __forceinline__ unsigned short f2bf_rne(float v) {
    unsigned u = __float_as_uint(v);
    unsigned r = (u + 0x7FFFu + ((u >> 16) & 1u)) >> 16;
    return (unsigned short)r;
}

// Stage one BK=32 chunk (64 rows). f32 path: 2 A + 4 B loads/thread (L=6).
// BF16A path: 1 A + 4 B loads/thread (L=5).
template <int K, bool BF16A>
__device__ __forceinline__ void stage_chunk(const float* __restrict__ A,
                                            const unsigned short* __restrict__ Ab,
                                            int rowbase,
                                            const unsigned short* __restrict__ Bp,
                                            int c, int tid, char* As, unsigned short* Bs) {
    const int w = tid >> 6;
    if (BF16A) {
        int row = tid & 63;
        int kk2lh = tid >> 6;
        const char* srcp = (const char*)Ab + ((size_t)(rowbase + row) * 128 + c * 32 + kk2lh * 8) * 2;
        char* dst = As + (size_t)(w * 64) * 16;
        __builtin_amdgcn_global_load_lds((const __attribute__((address_space(1))) void*)srcp,
                                         (__attribute__((address_space(3))) void*)dst, 16, 0, 0);
    } else {
#pragma unroll
        for (int q = 0; q < 2; ++q) {
            int lh = (tid >> 7) & 1;
            int row = (tid >> 1) & 63;
            int g = (tid & 1) ^ ((row >> 2) & 1);
            const float* srcp = A + (size_t)(rowbase + row) * K + c * 32 + q * 16 + lh * 8 + g * 4;
            char* dst = As + (size_t)(q * 256 + w * 64) * 16;
            __builtin_amdgcn_global_load_lds((const __attribute__((address_space(1))) void*)srcp,
                                             (__attribute__((address_space(3))) void*)dst, 16, 0, 0);
        }
    }
    const char* bsrc0 = (const char*)Bp + (size_t)c * 16384;
#pragma unroll
    for (int q = 0; q < 4; ++q) {
        const char* srcp = bsrc0 + (size_t)(q * 256 + tid) * 16;
        char* dst = (char*)Bs + (size_t)(q * 256 + w * 64) * 16;
        __builtin_amdgcn_global_load_lds((const __attribute__((address_space(1))) void*)srcp,
                                         (__attribute__((address_space(3))) void*)dst, 16, 0, 0);
    }
}

// Block: 64 rows x 128 cols, 4 waves, wave tile 32x64.
// 3-buffer LDS pipeline, counted vmcnt (never 0 in steady state), raw s_barrier.
template <int K, bool BF16A>
__global__ __launch_bounds__(256, 2) void k_gemm_mfma(const float* __restrict__ A,
                                                      const unsigned short* __restrict__ Ab,
                                                      const unsigned short* __restrict__ Bp,
                                                      unsigned short* __restrict__ Cb) {
    constexpr int NC = K / 32;
    __shared__ __align__(16) char As[3][8192];             // f32: 8KB; bf16A: first 4KB used
    __shared__ __align__(16) unsigned short Bs[3][8192];   // 3 x 16KB
    const int tid = threadIdx.x;
    const int w = tid >> 6;
    const int lane = tid & 63;
    const int l31 = lane & 31;
    const int lhalf = lane >> 5;
    const int rowbase = blockIdx.x * 64;
    const int ncol = (w & 1) * 2;
    const int r = (w >> 1) * 32 + l31;
    const int xr = (l31 >> 2) & 1;

    f32x16 acc[2] = {};

    stage_chunk<K, BF16A>(A, Ab, rowbase, Bp, 0, tid, As[0], Bs[0]);
    stage_chunk<K, BF16A>(A, Ab, rowbase, Bp, 1, tid, As[1], Bs[1]);

    for (int c = 0; c < NC; ++c) {
        if (c > 0) {
            __builtin_amdgcn_s_barrier();   // buf (c-1)%3 free
            asm volatile("" ::: "memory");
            __builtin_amdgcn_sched_barrier(0);
        }
        if (c + 2 < NC) {
            int b = (c + 2) % 3;
            stage_chunk<K, BF16A>(A, Ab, rowbase, Bp, c + 2, tid, As[b], Bs[b]);
        }
        int rem = NC - 1 - c;
        if (BF16A) {
            if (rem >= 2)      asm volatile("s_waitcnt vmcnt(10)" ::: "memory");
            else if (rem == 1) asm volatile("s_waitcnt vmcnt(5)" ::: "memory");
            else               asm volatile("s_waitcnt vmcnt(0)" ::: "memory");
        } else {
            if (rem >= 2)      asm volatile("s_waitcnt vmcnt(12)" ::: "memory");
            else if (rem == 1) asm volatile("s_waitcnt vmcnt(6)" ::: "memory");
            else               asm volatile("s_waitcnt vmcnt(0)" ::: "memory");
        }
        __builtin_amdgcn_s_barrier();       // chunk c visible
        const int cur = c % 3;
#pragma unroll
        for (int kk = 0; kk < 2; ++kk) {
            bf16x8 ahi, alo;
            if (BF16A) {
                int gidx = ((kk * 2 + lhalf) * 64 + r) * 16;
                ahi = *(const bf16x8*)&As[cur][gidx];
            } else {
                const float* Af = (const float*)As[cur];
                int bg = ((kk * 2 + lhalf) * 64 + r) * 2;
                float4 aa = *(const float4*)&Af[(size_t)(bg + xr) * 4];        // k+0..3
                float4 ab = *(const float4*)&Af[(size_t)(bg + (1 ^ xr)) * 4];  // k+4..7
                split8(aa, ab, ahi, alo);
            }
#pragma unroll
            for (int n = 0; n < 2; ++n) {
                int f = (ncol + n) * 2;
                bf16x8 bhi = *(const bf16x8*)&Bs[cur][(size_t)((kk * 8 + f) * 64 + lane) * 8];
                bf16x8 blo = *(const bf16x8*)&Bs[cur][(size_t)((kk * 8 + f + 1) * 64 + lane) * 8];
                acc[n] = __builtin_amdgcn_mfma_f32_32x32x16_bf16(ahi, bhi, acc[n], 0, 0, 0);
                acc[n] = __builtin_amdgcn_mfma_f32_32x32x16_bf16(ahi, blo, acc[n], 0, 0, 0);
                if (!BF16A)
                    acc[n] = __builtin_amdgcn_mfma_f32_32x32x16_bf16(alo, bhi, acc[n], 0, 0, 0);
            }
        }
    }

    const int rbase = rowbase + (w >> 1) * 32 + 4 * lhalf;
#pragma unroll
    for (int n = 0; n < 2; ++n) {
        const int col = (ncol + n) * 32 + l31;
#pragma unroll
        for (int rr = 0; rr < 16; ++rr) {
            int rout = rbase + (rr & 3) + 8 * (rr >> 2);
            Cb[(size_t)rout * HID + col] = f2bf_rne(acc[n][rr]);
        }
    }
}

// ---------------- aggregation: out[d] = di*(sum dinv[s]*ew*h[s]) + di^2*h[d] + b ----------------
// RELU=true: emit bf16 a1 (abuf). RELU=false: emit f32 to out.
__device__ __forceinline__ float2 up2(unsigned u) {
    float2 r;
    r.x = __uint_as_float(u << 16);
    r.y = __uint_as_float(u & 0xFFFF0000u);
    return r;
}

template <bool RELU>
__global__ __launch_bounds__(256) void k_agg(const unsigned short* __restrict__ hb,
                                             const float* __restrict__ dinv,
                                             const int* __restrict__ row_beg,
                                             const int* __restrict__ row_end,
                                             const uint2* __restrict__ edata,
                                             const float* __restrict__ bias,
                                             float* __restrict__ out,
                                             unsigned* __restrict__ abuf) {
    int d = (blockIdx.x * blockDim.x + threadIdx.x) >> 6;  // one wave per node
    int lane = threadIdx.x & 63;
    float di = dinv[d];
    float2 hv = up2(((const unsigned*)(hb + (size_t)d * HID))[lane]);
    int beg = row_beg[d], end = row_end[d];
    float ex = 0.f, ey = 0.f;
    int e = beg;
    for (; e + 15 < end; e += 16) {
        uint2 u[16];
        unsigned g[16];
        float dv[16];
#pragma unroll
        for (int q = 0; q < 16; q++) u[q] = edata[e + q];
#pragma unroll
        for (int q = 0; q < 16; q++) {
            g[q] = ((const unsigned*)(hb + (size_t)u[q].x * HID))[lane];
            dv[q] = dinv[u[q].x];
        }
#pragma unroll
        for (int q = 0; q < 16; q++) {
            float2 vv = up2(g[q]);
            float c = dv[q] * __uint_as_float(u[q].y);
            ex += c * vv.x;
            ey += c * vv.y;
        }
    }
    for (; e + 3 < end; e += 4) {
        uint2 u[4];
        unsigned g[4];
        float dv[4];
#pragma unroll
        for (int q = 0; q < 4; q++) u[q] = edata[e + q];
#pragma unroll
        for (int q = 0; q < 4; q++) {
            g[q] = ((const unsigned*)(hb + (size_t)u[q].x * HID))[lane];
            dv[q] = dinv[u[q].x];
        }
#pragma unroll
        for (int q = 0; q < 4; q++) {
            float2 vv = up2(g[q]);
            float c = dv[q] * __uint_as_float(u[q].y);
            ex += c * vv.x;
            ey += c * vv.y;
        }
    }
    for (; e < end; ++e) {
        uint2 u = edata[e];
        float2 v = up2(((const unsigned*)(hb + (size_t)u.x * HID))[lane]);
        float c = dinv[u.x] * __uint_as_float(u.y);
        ex += c * v.x;
        ey += c * v.y;
    }
    float2 bv = ((const float2*)bias)[lane];
    float selfc = di * di;
    float ax = di * ex + selfc * hv.x + bv.x;
    float ay = di * ey + selfc * hv.y + bv.y;
    if (RELU) {
        ax = fmaxf(ax, 0.f);
        ay = fmaxf(ay, 0.f);
        unsigned pk = (unsigned)f2bf_rne(ax) | ((unsigned)f2bf_rne(ay) << 16);
        abuf[(size_t)d * 64 + lane] = pk;
    } else {
        float2 rr;
        rr.x = ax;
        rr.y = ay;
        ((float2*)(out + (size_t)d * HID))[lane] = rr;
    }
}

extern "C" void kernel_launch(void* const* d_in, const int* in_sizes, int n_in,
                              void* d_out, int out_size, void* d_ws, size_t ws_size,
                              hipStream_t stream) {
    const float* x = (const float*)d_in[0];
    const int* ei = (const int*)d_in[1];
    const float* ew = (const float*)d_in[2];
    const float* W1 = (const float*)d_in[3];
    const float* b1 = (const float*)d_in[4];
    const float* W2 = (const float*)d_in[5];
    const float* b2 = (const float*)d_in[6];
    const int* src = ei;
    const int* dst = ei + NE;
    float* out = (float*)d_out;

    // Workspace layout — fully disjoint:
    char* ws = (char*)d_ws;
    unsigned short* hb = (unsigned short*)(ws + 0);          // 16 MB bf16 h
    uint2* edata    = (uint2*)(ws + 16777216);               //  8 MB final grouped edges
    int*   ghist    = (int*)(ws + 25165824);                 // 256 KB [256 bins][256 blocks]
    int*   bsum1    = (int*)(ws + 25427968);                 //  1 KB
    unsigned* e1sd  = (unsigned*)(ws + 25428992);            //  4 MB pass-1 packed (dsthi|src)
    float* e1ew     = (float*)(ws + 29623296);               //  4 MB pass-1 ew
    int*   row_beg  = (int*)(ws + 33817600);                 // 256 KB
    int*   row_end  = (int*)(ws + 34079744);                 // 256 KB
    float* dinv     = (float*)(ws + 34341888);               // 256 KB
    unsigned short* bp1 = (unsigned short*)(ws + 34604032);  // 256 KB
    unsigned short* bp2 = (unsigned short*)(ws + 34866176);  //  64 KB
    unsigned* a1b   = (unsigned*)(ws + 35651584);            //  16 MB bf16 a1

    // CSR build — zero global atomics, coarse (4096-edge) binning blocks:
    k_h1<<<NSB, 256, 0, stream>>>(dst, ghist);
    k_scan_ex<<<NSB, 256, 0, stream>>>(ghist, bsum1, 256 * NSB);
    k_scan_ex<<<1, 256, 0, stream>>>(bsum1, nullptr, NSB);
    k_addback<<<NSB, 256, 0, stream>>>(ghist, bsum1);
    k_s1<<<NSB, 256, 0, stream>>>(src, dst, ew, ghist, e1sd, e1ew);
    k_s2<<<256, 256, 0, stream>>>(ghist, e1sd, e1ew, edata, row_beg, row_end, dinv);
    k_prep_pack2<<<80, 256, 0, stream>>>(W1, bp1, W2, bp2);

    // layer 1: hb = bf16(x @ W1) ; a1 = relu(agg(hb) + b1) -> bf16 a1b
    k_gemm_mfma<INDIM, false><<<NN / 64, 256, 0, stream>>>(x, nullptr, bp1, hb);
    k_agg<true><<<NN / 4, 256, 0, stream>>>(hb, dinv, row_beg, row_end, edata, b1, nullptr, a1b);

    // layer 2: hb = bf16(a1 @ W2) ; z = agg(hb) + b2 -> d_out (f32)
    k_gemm_mfma<HID, true><<<NN / 64, 256, 0, stream>>>(nullptr, (const unsigned short*)a1b, bp2, hb);
    k_agg<false><<<NN / 4, 256, 0, stream>>>(hb, dinv, row_beg, row_end, edata, b2, out, nullptr);
}

// Round 15
// 188.006 us; speedup vs baseline: 2.1843x; 1.0586x over previous
//
#include <hip/hip_runtime.h>

#define NN 65536
#define NE 1048576
#define INDIM 512
#define HID 128
#define NSB 256   // binning blocks (4096 edges each)

typedef __attribute__((ext_vector_type(8))) short bf16x8;
typedef __attribute__((ext_vector_type(16))) float f32x16;

// ---------------- pass 1: per-block LDS histogram over lo8(dst), 4096 edges/block ----------------
__global__ void k_h1(const int* __restrict__ dst, int* __restrict__ ghist) {
    __shared__ int hcnt[256];
    hcnt[threadIdx.x] = 0;
    __syncthreads();
    int base = blockIdx.x * 4096;
#pragma unroll
    for (int r = 0; r < 16; r++)
        atomicAdd(&hcnt[dst[base + r * 256 + threadIdx.x] & 255], 1);  // LDS atomic
    __syncthreads();
    ghist[threadIdx.x * NSB + blockIdx.x] = hcnt[threadIdx.x];  // bin-major [bin][block]
}

// ---------------- generic 256-wide in-place exclusive scan level ----------------
__global__ void k_scan_ex(int* data, int* bsum, int n) {
    __shared__ int tmp[256];
    int i = blockIdx.x * 256 + threadIdx.x;
    int v = (i < n) ? data[i] : 0;
    tmp[threadIdx.x] = v;
    __syncthreads();
    for (int off = 1; off < 256; off <<= 1) {
        int t = (threadIdx.x >= off) ? tmp[threadIdx.x - off] : 0;
        __syncthreads();
        tmp[threadIdx.x] += t;
        __syncthreads();
    }
    if (i < n) data[i] = tmp[threadIdx.x] - v;  // exclusive
    if (threadIdx.x == 255 && bsum) bsum[blockIdx.x] = tmp[255];
}

// ---------------- pass 1 scatter: group edges by lo8(dst); cursors = bin base + local prefix ----------
// packed record: .x = (dst_hi8 << 16) | src   (src < 2^16), .y = ew bits
__global__ void k_s1(const int* __restrict__ src, const int* __restrict__ dst,
                     const float* __restrict__ ew, const int* __restrict__ ghist,
                     const int* __restrict__ bsum1, uint2* __restrict__ e1) {
    __shared__ int cur[256];
    cur[threadIdx.x] = bsum1[threadIdx.x] + ghist[threadIdx.x * NSB + blockIdx.x];
    __syncthreads();
    int base = blockIdx.x * 4096;
#pragma unroll
    for (int r = 0; r < 16; r++) {
        int e = base + r * 256 + threadIdx.x;
        int d = dst[e];
        int p = atomicAdd(&cur[d & 255], 1);  // LDS atomic; (block,bin) region private
        e1[p] = make_uint2((unsigned)src[e] | ((unsigned)(d >> 8) << 16), __float_as_uint(ew[e]));
    }
}

// ---------------- pass 2: one block per bin -> final dst-grouped edata + rows + dinv ----------------
__global__ void k_s2(const int* __restrict__ bsum1, const uint2* __restrict__ e1,
                     uint2* __restrict__ edata, int* __restrict__ row_beg,
                     int* __restrict__ row_end, float* __restrict__ dinv) {
    __shared__ int cnt[256];
    __shared__ float degs[256];
    __shared__ int tmp[256];
    __shared__ int curx[256];
    const int bin = blockIdx.x;
    const int t = threadIdx.x;
    cnt[t] = 0;
    degs[t] = 0.f;
    __syncthreads();
    const int binstart = bsum1[bin];
    const int binend = (bin == 255) ? NE : bsum1[bin + 1];
    for (int i = binstart + t; i < binend; i += 256) {
        uint2 u = e1[i];
        int j = u.x >> 16;
        atomicAdd(&cnt[j], 1);                       // LDS
        atomicAdd(&degs[j], __uint_as_float(u.y));   // LDS float
    }
    __syncthreads();
    // exclusive scan of cnt
    int v = cnt[t];
    tmp[t] = v;
    __syncthreads();
    for (int off = 1; off < 256; off <<= 1) {
        int u = (t >= off) ? tmp[t - off] : 0;
        __syncthreads();
        tmp[t] += u;
        __syncthreads();
    }
    int offt = tmp[t] - v;
    int d = (t << 8) | bin;
    int beg = binstart + offt;
    row_beg[d] = beg;
    row_end[d] = beg + v;
    dinv[d] = rsqrtf(1.0f + degs[t]);  // deg >= 1 (self-loop), ew >= 0
    curx[t] = beg;
    __syncthreads();
    for (int i = binstart + t; i < binend; i += 256) {
        uint2 u = e1[i];
        int p = atomicAdd(&curx[u.x >> 16], 1);  // LDS; same-dst edges stay contiguous
        edata[p] = make_uint2(u.x & 0xFFFFu, u.y);  // raw ew; dinv folded in agg
    }
}

// ---------------- W prep (fused W1+W2): f32 [K][128] -> MFMA-fragment-packed split-bf16 ----------------
__device__ __forceinline__ void prep_one(const float* __restrict__ W, unsigned short* __restrict__ P,
                                         int t) {
    int l = t & 63;
    int h = (t >> 6) & 1;
    int n = (t >> 7) & 3;
    int k0 = t >> 9;
    int colg = n * 32 + (l & 31);
    int kbase = k0 * 16 + (l >> 5) * 8;
    bf16x8 v;
#pragma unroll
    for (int j = 0; j < 8; j++) {
        float f = W[(size_t)(kbase + j) * 128 + colg];
        unsigned b = __float_as_uint(f);
        if (h == 0) {
            v[j] = (short)(b >> 16);
        } else {
            float lf = f - __uint_as_float(b & 0xFFFF0000u);
            v[j] = (short)(__float_as_uint(lf) >> 16);
        }
    }
    *(bf16x8*)(P + (size_t)t * 8) = v;
}

__global__ void k_prep_pack2(const float* __restrict__ W1, unsigned short* __restrict__ P1,
                             const float* __restrict__ W2, unsigned short* __restrict__ P2) {
    int t = blockIdx.x * 256 + threadIdx.x;
    if (t < 16384) prep_one(W1, P1, t);                      // K=512
    else if (t < 16384 + 4096) prep_one(W2, P2, t - 16384);  // K=128
}

// ---------------- split-bf16 MFMA GEMM: C[M,128] = A[M,K] @ W[K,128], C in bf16 ----------------
__device__ __forceinline__ void split8(const float4& a0, const float4& a1,
                                       bf16x8& hi, bf16x8& lo) {
    float f[8] = {a0.x, a0.y, a0.z, a0.w, a1.x, a1.y, a1.z, a1.w};
#pragma unroll
    for (int i = 0; i < 8; i++) {
        unsigned b = __float_as_uint(f[i]);
        unsigned hb = b & 0xFFFF0000u;
        float lf = f[i] - __uint_as_float(hb);
        hi[i] = (short)(hb >> 16);
        lo[i] = (short)(__float_as_uint(lf) >> 16);
    }
}

__device__ __forceinline__ unsigned short f2bf_rne(float v) {
    unsigned u = __float_as_uint(v);
    unsigned r = (u + 0x7FFFu + ((u >> 16) & 1u)) >> 16;
    return (unsigned short)r;
}

// Stage one BK=32 chunk (64 rows). f32 path: 2 A + 4 B loads/thread (L=6).
// BF16A path: 1 A + 4 B loads/thread (L=5).
template <int K, bool BF16A>
__device__ __forceinline__ void stage_chunk(const float* __restrict__ A,
                                            const unsigned short* __restrict__ Ab,
                                            int rowbase,
                                            const unsigned short* __restrict__ Bp,
                                            int c, int tid, char* As, unsigned short* Bs) {
    const int w = tid >> 6;
    if (BF16A) {
        int row = tid & 63;
        int kk2lh = tid >> 6;
        const char* srcp = (const char*)Ab + ((size_t)(rowbase + row) * 128 + c * 32 + kk2lh * 8) * 2;
        char* dst = As + (size_t)(w * 64) * 16;
        __builtin_amdgcn_global_load_lds((const __attribute__((address_space(1))) void*)srcp,
                                         (__attribute__((address_space(3))) void*)dst, 16, 0, 0);
    } else {
#pragma unroll
        for (int q = 0; q < 2; ++q) {
            int lh = (tid >> 7) & 1;
            int row = (tid >> 1) & 63;
            int g = (tid & 1) ^ ((row >> 2) & 1);
            const float* srcp = A + (size_t)(rowbase + row) * K + c * 32 + q * 16 + lh * 8 + g * 4;
            char* dst = As + (size_t)(q * 256 + w * 64) * 16;
            __builtin_amdgcn_global_load_lds((const __attribute__((address_space(1))) void*)srcp,
                                             (__attribute__((address_space(3))) void*)dst, 16, 0, 0);
        }
    }
    const char* bsrc0 = (const char*)Bp + (size_t)c * 16384;
#pragma unroll
    for (int q = 0; q < 4; ++q) {
        const char* srcp = bsrc0 + (size_t)(q * 256 + tid) * 16;
        char* dst = (char*)Bs + (size_t)(q * 256 + w * 64) * 16;
        __builtin_amdgcn_global_load_lds((const __attribute__((address_space(1))) void*)srcp,
                                         (__attribute__((address_space(3))) void*)dst, 16, 0, 0);
    }
}

// Block: 64 rows x 128 cols, 4 waves, wave tile 32x64.
// 3-buffer LDS pipeline, counted vmcnt (never 0 in steady state), raw s_barrier.
template <int K, bool BF16A>
__global__ __launch_bounds__(256, 2) void k_gemm_mfma(const float* __restrict__ A,
                                                      const unsigned short* __restrict__ Ab,
                                                      const unsigned short* __restrict__ Bp,
                                                      unsigned short* __restrict__ Cb) {
    constexpr int NC = K / 32;
    __shared__ __align__(16) char As[3][8192];             // f32: 8KB; bf16A: first 4KB used
    __shared__ __align__(16) unsigned short Bs[3][8192];   // 3 x 16KB
    const int tid = threadIdx.x;
    const int w = tid >> 6;
    const int lane = tid & 63;
    const int l31 = lane & 31;
    const int lhalf = lane >> 5;
    const int rowbase = blockIdx.x * 64;
    const int ncol = (w & 1) * 2;
    const int r = (w >> 1) * 32 + l31;
    const int xr = (l31 >> 2) & 1;

    f32x16 acc[2] = {};

    stage_chunk<K, BF16A>(A, Ab, rowbase, Bp, 0, tid, As[0], Bs[0]);
    stage_chunk<K, BF16A>(A, Ab, rowbase, Bp, 1, tid, As[1], Bs[1]);

    for (int c = 0; c < NC; ++c) {
        if (c > 0) {
            __builtin_amdgcn_s_barrier();   // buf (c-1)%3 free
            asm volatile("" ::: "memory");
            __builtin_amdgcn_sched_barrier(0);
        }
        if (c + 2 < NC) {
            int b = (c + 2) % 3;
            stage_chunk<K, BF16A>(A, Ab, rowbase, Bp, c + 2, tid, As[b], Bs[b]);
        }
        int rem = NC - 1 - c;
        if (BF16A) {
            if (rem >= 2)      asm volatile("s_waitcnt vmcnt(10)" ::: "memory");
            else if (rem == 1) asm volatile("s_waitcnt vmcnt(5)" ::: "memory");
            else               asm volatile("s_waitcnt vmcnt(0)" ::: "memory");
        } else {
            if (rem >= 2)      asm volatile("s_waitcnt vmcnt(12)" ::: "memory");
            else if (rem == 1) asm volatile("s_waitcnt vmcnt(6)" ::: "memory");
            else               asm volatile("s_waitcnt vmcnt(0)" ::: "memory");
        }
        __builtin_amdgcn_s_barrier();       // chunk c visible
        const int cur = c % 3;
#pragma unroll
        for (int kk = 0; kk < 2; ++kk) {
            bf16x8 ahi, alo;
            if (BF16A) {
                int gidx = ((kk * 2 + lhalf) * 64 + r) * 16;
                ahi = *(const bf16x8*)&As[cur][gidx];
            } else {
                const float* Af = (const float*)As[cur];
                int bg = ((kk * 2 + lhalf) * 64 + r) * 2;
                float4 aa = *(const float4*)&Af[(size_t)(bg + xr) * 4];        // k+0..3
                float4 ab = *(const float4*)&Af[(size_t)(bg + (1 ^ xr)) * 4];  // k+4..7
                split8(aa, ab, ahi, alo);
            }
#pragma unroll
            for (int n = 0; n < 2; ++n) {
                int f = (ncol + n) * 2;
                bf16x8 bhi = *(const bf16x8*)&Bs[cur][(size_t)((kk * 8 + f) * 64 + lane) * 8];
                bf16x8 blo = *(const bf16x8*)&Bs[cur][(size_t)((kk * 8 + f + 1) * 64 + lane) * 8];
                acc[n] = __builtin_amdgcn_mfma_f32_32x32x16_bf16(ahi, bhi, acc[n], 0, 0, 0);
                acc[n] = __builtin_amdgcn_mfma_f32_32x32x16_bf16(ahi, blo, acc[n], 0, 0, 0);
                if (!BF16A)
                    acc[n] = __builtin_amdgcn_mfma_f32_32x32x16_bf16(alo, bhi, acc[n], 0, 0, 0);
            }
        }
    }

    const int rbase = rowbase + (w >> 1) * 32 + 4 * lhalf;
#pragma unroll
    for (int n = 0; n < 2; ++n) {
        const int col = (ncol + n) * 32 + l31;
#pragma unroll
        for (int rr = 0; rr < 16; ++rr) {
            int rout = rbase + (rr & 3) + 8 * (rr >> 2);
            Cb[(size_t)rout * HID + col] = f2bf_rne(acc[n][rr]);
        }
    }
}

// ---------------- aggregation: out[d] = di*(sum dinv[s]*ew*h[s]) + di^2*h[d] + b ----------------
// RELU=true: emit bf16 a1 (abuf). RELU=false: emit f32 to out.
__device__ __forceinline__ float2 up2(unsigned u) {
    float2 r;
    r.x = __uint_as_float(u << 16);
    r.y = __uint_as_float(u & 0xFFFF0000u);
    return r;
}

template <bool RELU>
__global__ __launch_bounds__(256) void k_agg(const unsigned short* __restrict__ hb,
                                             const float* __restrict__ dinv,
                                             const int* __restrict__ row_beg,
                                             const int* __restrict__ row_end,
                                             const uint2* __restrict__ edata,
                                             const float* __restrict__ bias,
                                             float* __restrict__ out,
                                             unsigned* __restrict__ abuf) {
    int d = (blockIdx.x * blockDim.x + threadIdx.x) >> 6;  // one wave per node
    int lane = threadIdx.x & 63;
    float di = dinv[d];
    float2 hv = up2(((const unsigned*)(hb + (size_t)d * HID))[lane]);
    int beg = row_beg[d], end = row_end[d];
    float ex = 0.f, ey = 0.f;
    int e = beg;
    for (; e + 15 < end; e += 16) {
        uint2 u[16];
        unsigned g[16];
        float dv[16];
#pragma unroll
        for (int q = 0; q < 16; q++) u[q] = edata[e + q];
#pragma unroll
        for (int q = 0; q < 16; q++) {
            g[q] = ((const unsigned*)(hb + (size_t)u[q].x * HID))[lane];
            dv[q] = dinv[u[q].x];
        }
#pragma unroll
        for (int q = 0; q < 16; q++) {
            float2 vv = up2(g[q]);
            float c = dv[q] * __uint_as_float(u[q].y);
            ex += c * vv.x;
            ey += c * vv.y;
        }
    }
    for (; e + 3 < end; e += 4) {
        uint2 u[4];
        unsigned g[4];
        float dv[4];
#pragma unroll
        for (int q = 0; q < 4; q++) u[q] = edata[e + q];
#pragma unroll
        for (int q = 0; q < 4; q++) {
            g[q] = ((const unsigned*)(hb + (size_t)u[q].x * HID))[lane];
            dv[q] = dinv[u[q].x];
        }
#pragma unroll
        for (int q = 0; q < 4; q++) {
            float2 vv = up2(g[q]);
            float c = dv[q] * __uint_as_float(u[q].y);
            ex += c * vv.x;
            ey += c * vv.y;
        }
    }
    for (; e < end; ++e) {
        uint2 u = edata[e];
        float2 v = up2(((const unsigned*)(hb + (size_t)u.x * HID))[lane]);
        float c = dinv[u.x] * __uint_as_float(u.y);
        ex += c * v.x;
        ey += c * v.y;
    }
    float2 bv = ((const float2*)bias)[lane];
    float selfc = di * di;
    float ax = di * ex + selfc * hv.x + bv.x;
    float ay = di * ey + selfc * hv.y + bv.y;
    if (RELU) {
        ax = fmaxf(ax, 0.f);
        ay = fmaxf(ay, 0.f);
        unsigned pk = (unsigned)f2bf_rne(ax) | ((unsigned)f2bf_rne(ay) << 16);
        abuf[(size_t)d * 64 + lane] = pk;
    } else {
        float2 rr;
        rr.x = ax;
        rr.y = ay;
        ((float2*)(out + (size_t)d * HID))[lane] = rr;
    }
}

extern "C" void kernel_launch(void* const* d_in, const int* in_sizes, int n_in,
                              void* d_out, int out_size, void* d_ws, size_t ws_size,
                              hipStream_t stream) {
    const float* x = (const float*)d_in[0];
    const int* ei = (const int*)d_in[1];
    const float* ew = (const float*)d_in[2];
    const float* W1 = (const float*)d_in[3];
    const float* b1 = (const float*)d_in[4];
    const float* W2 = (const float*)d_in[5];
    const float* b2 = (const float*)d_in[6];
    const int* src = ei;
    const int* dst = ei + NE;
    float* out = (float*)d_out;

    // Workspace layout — fully disjoint:
    char* ws = (char*)d_ws;
    unsigned short* hb = (unsigned short*)(ws + 0);          // 16 MB bf16 h
    uint2* edata    = (uint2*)(ws + 16777216);               //  8 MB final grouped edges
    int*   ghist    = (int*)(ws + 25165824);                 // 256 KB [256 bins][256 blocks]
    int*   bsum1    = (int*)(ws + 25427968);                 //  1 KB
    uint2* e1       = (uint2*)(ws + 25428992);               //  8 MB pass-1 packed records
    int*   row_beg  = (int*)(ws + 33817600);                 // 256 KB
    int*   row_end  = (int*)(ws + 34079744);                 // 256 KB
    float* dinv     = (float*)(ws + 34341888);               // 256 KB
    unsigned short* bp1 = (unsigned short*)(ws + 34604032);  // 256 KB
    unsigned short* bp2 = (unsigned short*)(ws + 34866176);  //  64 KB
    unsigned* a1b   = (unsigned*)(ws + 35651584);            //  16 MB bf16 a1

    // CSR build — zero global atomics, coarse (4096-edge) binning blocks:
    k_h1<<<NSB, 256, 0, stream>>>(dst, ghist);
    k_scan_ex<<<NSB, 256, 0, stream>>>(ghist, bsum1, 256 * NSB);
    k_scan_ex<<<1, 256, 0, stream>>>(bsum1, nullptr, NSB);
    k_s1<<<NSB, 256, 0, stream>>>(src, dst, ew, ghist, bsum1, e1);
    k_s2<<<256, 256, 0, stream>>>(bsum1, e1, edata, row_beg, row_end, dinv);
    k_prep_pack2<<<80, 256, 0, stream>>>(W1, bp1, W2, bp2);

    // layer 1: hb = bf16(x @ W1) ; a1 = relu(agg(hb) + b1) -> bf16 a1b
    k_gemm_mfma<INDIM, false><<<NN / 64, 256, 0, stream>>>(x, nullptr, bp1, hb);
    k_agg<true><<<NN / 4, 256, 0, stream>>>(hb, dinv, row_beg, row_end, edata, b1, nullptr, a1b);

    // layer 2: hb = bf16(a1 @ W2) ; z = agg(hb) + b2 -> d_out (f32)
    k_gemm_mfma<HID, true><<<NN / 64, 256, 0, stream>>>(nullptr, (const unsigned short*)a1b, bp2, hb);
    k_agg<false><<<NN / 4, 256, 0, stream>>>(hb, dinv, row_beg, row_end, edata, b2, out, nullptr);
}

// Round 16
// 185.932 us; speedup vs baseline: 2.2087x; 1.0112x over previous
//
#include <hip/hip_runtime.h>

#define NN 65536
#define NE 1048576
#define INDIM 512
#define HID 128
#define NSB 256   // binning blocks (4096 edges each)

typedef __attribute__((ext_vector_type(8))) short bf16x8;
typedef __attribute__((ext_vector_type(16))) float f32x16;

// ---------------- W prep helper: f32 [K][128] -> MFMA-fragment-packed split-bf16 ----------------
__device__ __forceinline__ void prep_one(const float* __restrict__ W, unsigned short* __restrict__ P,
                                         int t) {
    int l = t & 63;
    int h = (t >> 6) & 1;
    int n = (t >> 7) & 3;
    int k0 = t >> 9;
    int colg = n * 32 + (l & 31);
    int kbase = k0 * 16 + (l >> 5) * 8;
    bf16x8 v;
#pragma unroll
    for (int j = 0; j < 8; j++) {
        float f = W[(size_t)(kbase + j) * 128 + colg];
        unsigned b = __float_as_uint(f);
        if (h == 0) {
            v[j] = (short)(b >> 16);
        } else {
            float lf = f - __uint_as_float(b & 0xFFFF0000u);
            v[j] = (short)(__float_as_uint(lf) >> 16);
        }
    }
    *(bf16x8*)(P + (size_t)t * 8) = v;
}

// ---------------- fused: per-block histogram (blocks < NSB) + weight prep (blocks >= NSB) ------
__global__ void k_h1p(const int* __restrict__ dst, int* __restrict__ ghist,
                      const float* __restrict__ W1, unsigned short* __restrict__ P1,
                      const float* __restrict__ W2, unsigned short* __restrict__ P2) {
    __shared__ int hcnt[256];
    const int b = blockIdx.x, t = threadIdx.x;
    if (b >= NSB) {
        int idx = (b - NSB) * 256 + t;
        if (idx < 16384) prep_one(W1, P1, idx);           // K=512
        else prep_one(W2, P2, idx - 16384);               // K=128 (idx < 20480 by grid size)
        return;
    }
    hcnt[t] = 0;
    __syncthreads();
    int base = b * 4096;
#pragma unroll
    for (int r = 0; r < 16; r++)
        atomicAdd(&hcnt[dst[base + r * 256 + t] & 255], 1);  // LDS atomic
    __syncthreads();
    ghist[t * NSB + b] = hcnt[t];  // bin-major [bin][block]
}

// ---------------- per-bin scan: block b scans bin b's 256 block-counts; bsum1[b] = bin total ----
__global__ void k_scan_ex(int* data, int* bsum, int n) {
    __shared__ int tmp[256];
    int i = blockIdx.x * 256 + threadIdx.x;
    int v = (i < n) ? data[i] : 0;
    tmp[threadIdx.x] = v;
    __syncthreads();
    for (int off = 1; off < 256; off <<= 1) {
        int t = (threadIdx.x >= off) ? tmp[threadIdx.x - off] : 0;
        __syncthreads();
        tmp[threadIdx.x] += t;
        __syncthreads();
    }
    if (i < n) data[i] = tmp[threadIdx.x] - v;  // exclusive within bin
    if (threadIdx.x == 255 && bsum) bsum[blockIdx.x] = tmp[255];  // bin total (raw)
}

// ---------------- pass 1 scatter: group edges by lo8(dst); bin bases scanned in-LDS ------------
// packed record: .x = (dst_hi8 << 16) | src   (src < 2^16), .y = ew bits
__global__ void k_s1(const int* __restrict__ src, const int* __restrict__ dst,
                     const float* __restrict__ ew, const int* __restrict__ ghist,
                     const int* __restrict__ bsum1, uint2* __restrict__ e1) {
    __shared__ int cur[256];
    const int t = threadIdx.x;
    // exclusive scan of raw bin totals -> bin base for bin t
    int v = bsum1[t];
    cur[t] = v;
    __syncthreads();
    for (int off = 1; off < 256; off <<= 1) {
        int u = (t >= off) ? cur[t - off] : 0;
        __syncthreads();
        cur[t] += u;
        __syncthreads();
    }
    int binbase = cur[t] - v;
    __syncthreads();
    cur[t] = binbase + ghist[t * NSB + blockIdx.x];  // + within-bin prefix of this block
    __syncthreads();
    int base = blockIdx.x * 4096;
#pragma unroll
    for (int r = 0; r < 16; r++) {
        int e = base + r * 256 + t;
        int d = dst[e];
        int p = atomicAdd(&cur[d & 255], 1);  // LDS atomic; (block,bin) region private
        e1[p] = make_uint2((unsigned)src[e] | ((unsigned)(d >> 8) << 16), __float_as_uint(ew[e]));
    }
}

// ---------------- pass 2: one block per bin -> final dst-grouped edata + rows + dinv ----------------
__global__ void k_s2(const int* __restrict__ bsum1, const uint2* __restrict__ e1,
                     uint2* __restrict__ edata, int* __restrict__ row_beg,
                     int* __restrict__ row_end, float* __restrict__ dinv) {
    __shared__ int cnt[256];
    __shared__ float degs[256];
    __shared__ int tmp[256];
    __shared__ int curx[256];
    const int bin = blockIdx.x;
    const int t = threadIdx.x;
    // scan raw bin totals -> bases; broadcast this bin's [start, end)
    int v = bsum1[t];
    tmp[t] = v;
    cnt[t] = v;  // keep raw totals for binend
    __syncthreads();
    for (int off = 1; off < 256; off <<= 1) {
        int u = (t >= off) ? tmp[t - off] : 0;
        __syncthreads();
        tmp[t] += u;
        __syncthreads();
    }
    curx[t] = tmp[t] - v;  // bin base
    __syncthreads();
    const int binstart = curx[bin];
    const int binend = binstart + cnt[bin];
    __syncthreads();
    cnt[t] = 0;
    degs[t] = 0.f;
    __syncthreads();
    for (int i = binstart + t; i < binend; i += 256) {
        uint2 u = e1[i];
        int j = u.x >> 16;
        atomicAdd(&cnt[j], 1);                       // LDS
        atomicAdd(&degs[j], __uint_as_float(u.y));   // LDS float
    }
    __syncthreads();
    // exclusive scan of cnt
    int c = cnt[t];
    tmp[t] = c;
    __syncthreads();
    for (int off = 1; off < 256; off <<= 1) {
        int u = (t >= off) ? tmp[t - off] : 0;
        __syncthreads();
        tmp[t] += u;
        __syncthreads();
    }
    int offt = tmp[t] - c;
    int d = (t << 8) | bin;
    int beg = binstart + offt;
    row_beg[d] = beg;
    row_end[d] = beg + c;
    dinv[d] = rsqrtf(1.0f + degs[t]);  // deg >= 1 (self-loop), ew >= 0
    curx[t] = beg;
    __syncthreads();
    for (int i = binstart + t; i < binend; i += 256) {
        uint2 u = e1[i];
        int p = atomicAdd(&curx[u.x >> 16], 1);  // LDS; same-dst edges stay contiguous
        edata[p] = make_uint2(u.x & 0xFFFFu, u.y);  // raw ew; dinv folded in agg
    }
}

// ---------------- split-bf16 MFMA GEMM: C[M,128] = A[M,K] @ W[K,128], C in bf16 ----------------
__device__ __forceinline__ void split8(const float4& a0, const float4& a1,
                                       bf16x8& hi, bf16x8& lo) {
    float f[8] = {a0.x, a0.y, a0.z, a0.w, a1.x, a1.y, a1.z, a1.w};
#pragma unroll
    for (int i = 0; i < 8; i++) {
        unsigned b = __float_as_uint(f[i]);
        unsigned hb = b & 0xFFFF0000u;
        float lf = f[i] - __uint_as_float(hb);
        hi[i] = (short)(hb >> 16);
        lo[i] = (short)(__float_as_uint(lf) >> 16);
    }
}

__device__ __forceinline__ unsigned short f2bf_rne(float v) {
    unsigned u = __float_as_uint(v);
    unsigned r = (u + 0x7FFFu + ((u >> 16) & 1u)) >> 16;
    return (unsigned short)r;
}

// Stage one BK=32 chunk (64 rows). f32 path: 2 A + 4 B loads/thread (L=6).
// BF16A path: 1 A + 4 B loads/thread (L=5).
template <int K, bool BF16A>
__device__ __forceinline__ void stage_chunk(const float* __restrict__ A,
                                            const unsigned short* __restrict__ Ab,
                                            int rowbase,
                                            const unsigned short* __restrict__ Bp,
                                            int c, int tid, char* As, unsigned short* Bs) {
    const int w = tid >> 6;
    if (BF16A) {
        int row = tid & 63;
        int kk2lh = tid >> 6;
        const char* srcp = (const char*)Ab + ((size_t)(rowbase + row) * 128 + c * 32 + kk2lh * 8) * 2;
        char* dst = As + (size_t)(w * 64) * 16;
        __builtin_amdgcn_global_load_lds((const __attribute__((address_space(1))) void*)srcp,
                                         (__attribute__((address_space(3))) void*)dst, 16, 0, 0);
    } else {
#pragma unroll
        for (int q = 0; q < 2; ++q) {
            int lh = (tid >> 7) & 1;
            int row = (tid >> 1) & 63;
            int g = (tid & 1) ^ ((row >> 2) & 1);
            const float* srcp = A + (size_t)(rowbase + row) * K + c * 32 + q * 16 + lh * 8 + g * 4;
            char* dst = As + (size_t)(q * 256 + w * 64) * 16;
            __builtin_amdgcn_global_load_lds((const __attribute__((address_space(1))) void*)srcp,
                                             (__attribute__((address_space(3))) void*)dst, 16, 0, 0);
        }
    }
    const char* bsrc0 = (const char*)Bp + (size_t)c * 16384;
#pragma unroll
    for (int q = 0; q < 4; ++q) {
        const char* srcp = bsrc0 + (size_t)(q * 256 + tid) * 16;
        char* dst = (char*)Bs + (size_t)(q * 256 + w * 64) * 16;
        __builtin_amdgcn_global_load_lds((const __attribute__((address_space(1))) void*)srcp,
                                         (__attribute__((address_space(3))) void*)dst, 16, 0, 0);
    }
}

// Block: 64 rows x 128 cols, 4 waves, wave tile 32x64.
// 3-buffer LDS pipeline, counted vmcnt (never 0 in steady state), raw s_barrier.
template <int K, bool BF16A>
__global__ __launch_bounds__(256, 2) void k_gemm_mfma(const float* __restrict__ A,
                                                      const unsigned short* __restrict__ Ab,
                                                      const unsigned short* __restrict__ Bp,
                                                      unsigned short* __restrict__ Cb) {
    constexpr int NC = K / 32;
    __shared__ __align__(16) char As[3][8192];             // f32: 8KB; bf16A: first 4KB used
    __shared__ __align__(16) unsigned short Bs[3][8192];   // 3 x 16KB
    const int tid = threadIdx.x;
    const int w = tid >> 6;
    const int lane = tid & 63;
    const int l31 = lane & 31;
    const int lhalf = lane >> 5;
    const int rowbase = blockIdx.x * 64;
    const int ncol = (w & 1) * 2;
    const int r = (w >> 1) * 32 + l31;
    const int xr = (l31 >> 2) & 1;

    f32x16 acc[2] = {};

    stage_chunk<K, BF16A>(A, Ab, rowbase, Bp, 0, tid, As[0], Bs[0]);
    stage_chunk<K, BF16A>(A, Ab, rowbase, Bp, 1, tid, As[1], Bs[1]);

    for (int c = 0; c < NC; ++c) {
        if (c > 0) {
            __builtin_amdgcn_s_barrier();   // buf (c-1)%3 free
            asm volatile("" ::: "memory");
            __builtin_amdgcn_sched_barrier(0);
        }
        if (c + 2 < NC) {
            int b = (c + 2) % 3;
            stage_chunk<K, BF16A>(A, Ab, rowbase, Bp, c + 2, tid, As[b], Bs[b]);
        }
        int rem = NC - 1 - c;
        if (BF16A) {
            if (rem >= 2)      asm volatile("s_waitcnt vmcnt(10)" ::: "memory");
            else if (rem == 1) asm volatile("s_waitcnt vmcnt(5)" ::: "memory");
            else               asm volatile("s_waitcnt vmcnt(0)" ::: "memory");
        } else {
            if (rem >= 2)      asm volatile("s_waitcnt vmcnt(12)" ::: "memory");
            else if (rem == 1) asm volatile("s_waitcnt vmcnt(6)" ::: "memory");
            else               asm volatile("s_waitcnt vmcnt(0)" ::: "memory");
        }
        __builtin_amdgcn_s_barrier();       // chunk c visible
        const int cur = c % 3;
#pragma unroll
        for (int kk = 0; kk < 2; ++kk) {
            bf16x8 ahi, alo;
            if (BF16A) {
                int gidx = ((kk * 2 + lhalf) * 64 + r) * 16;
                ahi = *(const bf16x8*)&As[cur][gidx];
            } else {
                const float* Af = (const float*)As[cur];
                int bg = ((kk * 2 + lhalf) * 64 + r) * 2;
                float4 aa = *(const float4*)&Af[(size_t)(bg + xr) * 4];        // k+0..3
                float4 ab = *(const float4*)&Af[(size_t)(bg + (1 ^ xr)) * 4];  // k+4..7
                split8(aa, ab, ahi, alo);
            }
#pragma unroll
            for (int n = 0; n < 2; ++n) {
                int f = (ncol + n) * 2;
                bf16x8 bhi = *(const bf16x8*)&Bs[cur][(size_t)((kk * 8 + f) * 64 + lane) * 8];
                bf16x8 blo = *(const bf16x8*)&Bs[cur][(size_t)((kk * 8 + f + 1) * 64 + lane) * 8];
                acc[n] = __builtin_amdgcn_mfma_f32_32x32x16_bf16(ahi, bhi, acc[n], 0, 0, 0);
                acc[n] = __builtin_amdgcn_mfma_f32_32x32x16_bf16(ahi, blo, acc[n], 0, 0, 0);
                if (!BF16A)
                    acc[n] = __builtin_amdgcn_mfma_f32_32x32x16_bf16(alo, bhi, acc[n], 0, 0, 0);
            }
        }
    }

    const int rbase = rowbase + (w >> 1) * 32 + 4 * lhalf;
#pragma unroll
    for (int n = 0; n < 2; ++n) {
        const int col = (ncol + n) * 32 + l31;
#pragma unroll
        for (int rr = 0; rr < 16; ++rr) {
            int rout = rbase + (rr & 3) + 8 * (rr >> 2);
            Cb[(size_t)rout * HID + col] = f2bf_rne(acc[n][rr]);
        }
    }
}

// ---------------- aggregation: out[d] = di*(sum dinv[s]*ew*h[s]) + di^2*h[d] + b ----------------
// RELU=true: emit bf16 a1 (abuf). RELU=false: emit f32 to out.
__device__ __forceinline__ float2 up2(unsigned u) {
    float2 r;
    r.x = __uint_as_float(u << 16);
    r.y = __uint_as_float(u & 0xFFFF0000u);
    return r;
}

template <bool RELU>
__global__ __launch_bounds__(256) void k_agg(const unsigned short* __restrict__ hb,
                                             const float* __restrict__ dinv,
                                             const int* __restrict__ row_beg,
                                             const int* __restrict__ row_end,
                                             const uint2* __restrict__ edata,
                                             const float* __restrict__ bias,
                                             float* __restrict__ out,
                                             unsigned* __restrict__ abuf) {
    int d = (blockIdx.x * blockDim.x + threadIdx.x) >> 6;  // one wave per node
    int lane = threadIdx.x & 63;
    float di = dinv[d];
    float2 hv = up2(((const unsigned*)(hb + (size_t)d * HID))[lane]);
    int beg = row_beg[d], end = row_end[d];
    float ex = 0.f, ey = 0.f;
    int e = beg;
    for (; e + 15 < end; e += 16) {
        uint2 u[16];
        unsigned g[16];
        float dv[16];
#pragma unroll
        for (int q = 0; q < 16; q++) u[q] = edata[e + q];
#pragma unroll
        for (int q = 0; q < 16; q++) {
            g[q] = ((const unsigned*)(hb + (size_t)u[q].x * HID))[lane];
            dv[q] = dinv[u[q].x];
        }
#pragma unroll
        for (int q = 0; q < 16; q++) {
            float2 vv = up2(g[q]);
            float c = dv[q] * __uint_as_float(u[q].y);
            ex += c * vv.x;
            ey += c * vv.y;
        }
    }
    for (; e + 3 < end; e += 4) {
        uint2 u[4];
        unsigned g[4];
        float dv[4];
#pragma unroll
        for (int q = 0; q < 4; q++) u[q] = edata[e + q];
#pragma unroll
        for (int q = 0; q < 4; q++) {
            g[q] = ((const unsigned*)(hb + (size_t)u[q].x * HID))[lane];
            dv[q] = dinv[u[q].x];
        }
#pragma unroll
        for (int q = 0; q < 4; q++) {
            float2 vv = up2(g[q]);
            float c = dv[q] * __uint_as_float(u[q].y);
            ex += c * vv.x;
            ey += c * vv.y;
        }
    }
    for (; e < end; ++e) {
        uint2 u = edata[e];
        float2 v = up2(((const unsigned*)(hb + (size_t)u.x * HID))[lane]);
        float c = dinv[u.x] * __uint_as_float(u.y);
        ex += c * v.x;
        ey += c * v.y;
    }
    float2 bv = ((const float2*)bias)[lane];
    float selfc = di * di;
    float ax = di * ex + selfc * hv.x + bv.x;
    float ay = di * ey + selfc * hv.y + bv.y;
    if (RELU) {
        ax = fmaxf(ax, 0.f);
        ay = fmaxf(ay, 0.f);
        unsigned pk = (unsigned)f2bf_rne(ax) | ((unsigned)f2bf_rne(ay) << 16);
        abuf[(size_t)d * 64 + lane] = pk;
    } else {
        float2 rr;
        rr.x = ax;
        rr.y = ay;
        ((float2*)(out + (size_t)d * HID))[lane] = rr;
    }
}

extern "C" void kernel_launch(void* const* d_in, const int* in_sizes, int n_in,
                              void* d_out, int out_size, void* d_ws, size_t ws_size,
                              hipStream_t stream) {
    const float* x = (const float*)d_in[0];
    const int* ei = (const int*)d_in[1];
    const float* ew = (const float*)d_in[2];
    const float* W1 = (const float*)d_in[3];
    const float* b1 = (const float*)d_in[4];
    const float* W2 = (const float*)d_in[5];
    const float* b2 = (const float*)d_in[6];
    const int* src = ei;
    const int* dst = ei + NE;
    float* out = (float*)d_out;

    // Workspace layout — fully disjoint:
    char* ws = (char*)d_ws;
    unsigned short* hb = (unsigned short*)(ws + 0);          // 16 MB bf16 h
    uint2* edata    = (uint2*)(ws + 16777216);               //  8 MB final grouped edges
    int*   ghist    = (int*)(ws + 25165824);                 // 256 KB [256 bins][256 blocks]
    int*   bsum1    = (int*)(ws + 25427968);                 //  1 KB raw bin totals
    uint2* e1       = (uint2*)(ws + 25428992);               //  8 MB pass-1 packed records
    int*   row_beg  = (int*)(ws + 33817600);                 // 256 KB
    int*   row_end  = (int*)(ws + 34079744);                 // 256 KB
    float* dinv     = (float*)(ws + 34341888);               // 256 KB
    unsigned short* bp1 = (unsigned short*)(ws + 34604032);  // 256 KB
    unsigned short* bp2 = (unsigned short*)(ws + 34866176);  //  64 KB
    unsigned* a1b   = (unsigned*)(ws + 35651584);            //  16 MB bf16 a1

    // CSR build + weight prep — zero global atomics, 8 launches total:
    k_h1p<<<NSB + 80, 256, 0, stream>>>(dst, ghist, W1, bp1, W2, bp2);
    k_scan_ex<<<NSB, 256, 0, stream>>>(ghist, bsum1, 256 * NSB);
    k_s1<<<NSB, 256, 0, stream>>>(src, dst, ew, ghist, bsum1, e1);
    k_s2<<<256, 256, 0, stream>>>(bsum1, e1, edata, row_beg, row_end, dinv);

    // layer 1: hb = bf16(x @ W1) ; a1 = relu(agg(hb) + b1) -> bf16 a1b
    k_gemm_mfma<INDIM, false><<<NN / 64, 256, 0, stream>>>(x, nullptr, bp1, hb);
    k_agg<true><<<NN / 4, 256, 0, stream>>>(hb, dinv, row_beg, row_end, edata, b1, nullptr, a1b);

    // layer 2: hb = bf16(a1 @ W2) ; z = agg(hb) + b2 -> d_out (f32)
    k_gemm_mfma<HID, true><<<NN / 64, 256, 0, stream>>>(nullptr, (const unsigned short*)a1b, bp2, hb);
    k_agg<false><<<NN / 4, 256, 0, stream>>>(hb, dinv, row_beg, row_end, edata, b2, out, nullptr);
}